// Round 21
// baseline (2772.993 us; speedup 1.0000x reference)
//
#include <hip/hip_runtime.h>
#include <stdint.h>

#define T_ 512
#define B_ 64
#define IN_ 512
#define H_ 1024
#define RB 16
#define LNEPS 1e-5f
#define ZSCALE 2.885390081777927f  // 2*log2(e): tanh(y) via exp2(z), z = ZSCALE*y
#define FL(t, rg) (((t) * 4 + (rg)) * 32)  // ushort index: 64B line, 32 u16 stamps

typedef __attribute__((ext_vector_type(8))) _Float16 h16x8;
typedef __attribute__((ext_vector_type(2))) _Float16 h16x2;
typedef __attribute__((ext_vector_type(4))) float f32x4;
typedef __attribute__((ext_vector_type(4))) float float4v;
typedef __attribute__((ext_vector_type(4))) int int4v;
typedef unsigned short ushort_t;

__device__ __forceinline__ h16x8 ldw8h(const float* p) {
  float4v a = *(const float4v*)p;
  float4v b = *(const float4v*)(p + 4);
  h16x8 o;
  o[0] = (_Float16)a[0]; o[1] = (_Float16)a[1]; o[2] = (_Float16)a[2]; o[3] = (_Float16)a[3];
  o[4] = (_Float16)b[0]; o[5] = (_Float16)b[1]; o[6] = (_Float16)b[2]; o[7] = (_Float16)b[3];
  return o;
}
#define PIN8(x) asm volatile("" : "+v"(x))

// ---- MALL-scope (sc0 sc1) stores + u16 stamp/poll sync (only safe inter-block point;
// R17 proved L2-scope signaling strands stamps in the producer's L2) ----
__device__ __forceinline__ void sth_sys(ushort_t* p, float v) {
  _Float16 h = (_Float16)v;
  int s = (int)__builtin_bit_cast(short, h);
  asm volatile("global_store_short %0, %1, off sc0 sc1" :: "v"(p), "v"(s) : "memory");
}
__device__ __forceinline__ void relfence() { asm volatile("s_waitcnt vmcnt(0)" ::: "memory"); }
__device__ __forceinline__ void stamp16(ushort_t* p, int v) {
  asm volatile("global_store_short %0, %1, off sc0 sc1" :: "v"(p), "v"(v) : "memory");
}
// poll one 64B line (32 u16 stamps) until min >= target
__device__ __forceinline__ void poll32h(const ushort_t* p, int target) {
  int n = 0;
  while (true) {
    int4v a, b, c, d;
    asm volatile(
        "global_load_dwordx4 %0, %4, off sc0 sc1\n\t"
        "global_load_dwordx4 %1, %4, off offset:16 sc0 sc1\n\t"
        "global_load_dwordx4 %2, %4, off offset:32 sc0 sc1\n\t"
        "global_load_dwordx4 %3, %4, off offset:48 sc0 sc1\n\t"
        "s_waitcnt vmcnt(0)"
        : "=&v"(a), "=&v"(b), "=&v"(c), "=&v"(d) : "v"(p) : "memory");
    int mn = 0xFFFF;
#pragma unroll
    for (int i = 0; i < 4; ++i) {
      unsigned u0 = (unsigned)a[i], u1 = (unsigned)b[i], u2 = (unsigned)c[i], u3 = (unsigned)d[i];
      mn = min(mn, (int)(u0 & 0xFFFFu)); mn = min(mn, (int)(u0 >> 16));
      mn = min(mn, (int)(u1 & 0xFFFFu)); mn = min(mn, (int)(u1 >> 16));
      mn = min(mn, (int)(u2 & 0xFFFFu)); mn = min(mn, (int)(u2 >> 16));
      mn = min(mn, (int)(u3 & 0xFFFFu)); mn = min(mn, (int)(u3 >> 16));
    }
    if (mn >= target) return;
    if (n < 4) __builtin_amdgcn_s_sleep(1);
    else __builtin_amdgcn_s_sleep(4);
    if (++n > 2000000) return;  // safety: wrong data instead of hang
  }
}

// LDS swizzle (ushort units): chunk = 8 u16 (16B); low2 = ((ch>>3)^ch^r)&3
__device__ __forceinline__ int chix(int r, int c) {
  int ch = c >> 3;
  int low = ((ch >> 3) ^ ch ^ r) & 3;
  return r * 1032 + ((((ch >> 2) << 2) | low) << 3) + (c & 7);
}

// ---- staging: 512 threads; r=tid>>5 in 0..15, k=tid&31 owns cols [32k,32k+32) ----
__device__ __forceinline__ void stageHf(const float* src, ushort_t* dA, int tid) {
  int r = tid >> 5, k = tid & 31, c0 = k * 32;
  const float* p = src + (size_t)r * H_ + c0;
#pragma unroll
  for (int q = 0; q < 4; ++q) {
    float4v a = *(const float4v*)(p + q * 8);
    float4v b = *(const float4v*)(p + q * 8 + 4);
    h16x8 h;
    h[0] = (_Float16)a[0]; h[1] = (_Float16)a[1]; h[2] = (_Float16)a[2]; h[3] = (_Float16)a[3];
    h[4] = (_Float16)b[0]; h[5] = (_Float16)b[1]; h[6] = (_Float16)b[2]; h[7] = (_Float16)b[3];
    *(h16x8*)&dA[chix(r, c0 + q * 8)] = h;
  }
}
__device__ __forceinline__ void stageXh(const float* src, ushort_t* dA, int tid) {
  int r = tid >> 5, k = tid & 31, c0 = k * 16;
  const float* p = src + (size_t)r * IN_ + c0;
#pragma unroll
  for (int q = 0; q < 2; ++q) {
    float4v a = *(const float4v*)(p + q * 8);
    float4v b = *(const float4v*)(p + q * 8 + 4);
    h16x8 h;
    h[0] = (_Float16)a[0]; h[1] = (_Float16)a[1]; h[2] = (_Float16)a[2]; h[3] = (_Float16)a[3];
    h[4] = (_Float16)b[0]; h[5] = (_Float16)b[1]; h[6] = (_Float16)b[2]; h[7] = (_Float16)b[3];
    *(h16x8*)&dA[chix(r, c0 + q * 8)] = h;
  }
}
// raw fp16 slab loads (plain path; write-once addresses)
__device__ __forceinline__ void ldraw4(const ushort_t* src, h16x8 (&raw)[4], int tid) {
  int r = tid >> 5, k = tid & 31, c0 = k * 32;
  const ushort_t* p = src + (size_t)r * H_ + c0;
#pragma unroll
  for (int q = 0; q < 4; ++q) raw[q] = *(const h16x8*)(p + q * 8);
}
// LN+tanh on a raw fp16 slab -> fp16 LDS. Packed-fp16 LN apply + dot2 stats +
// native fp16 transcendental tail (v_exp_f16 / v_rcp_f16 — no f32 conversions).
__device__ __forceinline__ void procLTh(const h16x8 (&raw)[4], ushort_t* dA,
                                        const _Float16* lnw, const _Float16* lnbz, int tid,
                                        int cg, bool wr, float* gA, float* gB) {
  int r = tid >> 5, k = tid & 31, c0 = k * 32;
  const h16x2 one2 = {(_Float16)1.f, (_Float16)1.f};
  float s = 0.f, ss = 0.f;
#pragma unroll
  for (int q = 0; q < 4; ++q) {
#pragma unroll
    for (int pp = 0; pp < 4; ++pp) {
      h16x2 xp;
      xp[0] = raw[q][2 * pp]; xp[1] = raw[q][2 * pp + 1];
      s = __builtin_amdgcn_fdot2(xp, one2, s, false);
      ss = __builtin_amdgcn_fdot2(xp, xp, ss, false);
    }
  }
#pragma unroll
  for (int m = 1; m <= 16; m <<= 1) { s += __shfl_xor(s, m, 64); ss += __shfl_xor(ss, m, 64); }
  float mu = s * (1.f / H_);
  float var = ss * (1.f / H_) - mu * mu;
  float zrs = rsqrtf(var + LNEPS) * ZSCALE;
  _Float16 muh = (_Float16)mu, zrsh = (_Float16)zrs;
  h16x2 mu2 = {muh, muh}, zrs2 = {zrsh, zrsh};
  const h16x2 zlo2 = {(_Float16)-15.5f, (_Float16)-15.5f};
  const h16x2 zhi2 = {(_Float16)15.5f, (_Float16)15.5f};
#pragma unroll
  for (int q = 0; q < 4; ++q) {
    h16x8 wv = *(const h16x8*)&lnw[q * 256 + k * 8];
    h16x8 bzv = *(const h16x8*)&lnbz[q * 256 + k * 8];
    h16x8 hout;
#pragma unroll
    for (int pp = 0; pp < 4; ++pp) {
      h16x2 xp, wp, bp;
      xp[0] = raw[q][2 * pp]; xp[1] = raw[q][2 * pp + 1];
      wp[0] = wv[2 * pp];     wp[1] = wv[2 * pp + 1];
      bp[0] = bzv[2 * pp];    bp[1] = bzv[2 * pp + 1];
      h16x2 z2 = (xp - mu2) * zrs2 * wp + bp;  // z = ZSCALE * y, packed fp16
      asm("v_pk_max_f16 %0, %1, %2" : "=v"(z2) : "v"(z2), "v"(zlo2));
      asm("v_pk_min_f16 %0, %1, %2" : "=v"(z2) : "v"(z2), "v"(zhi2));
#pragma unroll
      for (int e = 0; e < 2; ++e) {
        _Float16 z = z2[e];
        _Float16 ex;
        asm("v_exp_f16 %0, %1" : "=v"(ex) : "v"(z));      // 2^z = e^{2y}, fp16
        _Float16 dn = ex + (_Float16)1.0f;
        _Float16 rr;
        asm("v_rcp_f16 %0, %1" : "=v"(rr) : "v"(dn));
        hout[2 * pp + e] = (_Float16)1.0f - (_Float16)2.0f * rr;  // tanh(y)
      }
    }
    *(h16x8*)&dA[chix(r, c0 + q * 8)] = hout;
    if (wr && k == cg) {
      float hf[8];
#pragma unroll
      for (int j = 0; j < 8; ++j) hf[j] = (float)hout[j];
      float* pa = gA + (size_t)r * H_ + c0 + q * 8;
      *(float4v*)pa = (float4v){hf[0], hf[1], hf[2], hf[3]};
      *(float4v*)(pa + 4) = (float4v){hf[4], hf[5], hf[6], hf[7]};
      if (gB) {
        float* pb = gB + (size_t)r * H_ + c0 + q * 8;
        *(float4v*)pb = (float4v){hf[0], hf[1], hf[2], hf[3]};
        *(float4v*)(pb + 4) = (float4v){hf[4], hf[5], hf[6], hf[7]};
      }
    }
  }
}
__device__ __forceinline__ void stageLTh(const ushort_t* src, ushort_t* dA,
                                         const _Float16* lnw, const _Float16* lnbz, int tid,
                                         int cg, bool wr, float* gA, float* gB) {
  h16x8 raw[4];
  ldraw4(src, raw, tid);
  procLTh(raw, dA, lnw, lnbz, tid, cg, wr, gA, gB);
}

#define MFMA(a, b, c) __builtin_amdgcn_mfma_f32_16x16x32_f16(a, b, c, 0, 0, 0)
#define AF(buf, idx) (*(const h16x8*)&buf[chix(lane & 15, (idx) + kb8)])

// geometry: 256 blocks; XCD-pinned mapping: layer=(blk>>2)&1, rg=blk&3, cg=blk>>3
__global__ __launch_bounds__(512, 1) void rnn_persist(
    const float* __restrict__ input, const float* __restrict__ hidden,
    const float* __restrict__ W_ih0, const float* __restrict__ W_hh0,
    const float* __restrict__ b_ih0, const float* __restrict__ b_hh0,
    const float* __restrict__ ln_w0, const float* __restrict__ ln_b0,
    const float* __restrict__ W_ih1, const float* __restrict__ W_hh1,
    const float* __restrict__ b_ih1, const float* __restrict__ b_hh1,
    const float* __restrict__ ln_w1, const float* __restrict__ ln_b1,
    float* gout, ushort_t* pre0, ushort_t* pre1,
    ushort_t* flag0a, ushort_t* flag0b, ushort_t* flag1a) {
  __shared__ ushort_t sA[16 * 1032];
  __shared__ ushort_t sA1[16 * 1032];   // L1 double buffer (stage1 overlaps WB MFMA)
  __shared__ _Float16 slnw0h[1024], slnbz0h[1024];
  __shared__ _Float16 slnw1h[1024], slnbz1h[1024];
  __shared__ float sacc[3][2][16][16];

  const int tid = threadIdx.x;
  const int lane = tid & 63;
  const int w = tid >> 6;
  const int colt = w & 1, kh = w >> 1;  // 2 col-tiles x 4 K-quarters
  const int blk = blockIdx.x;
  const int layer = (blk >> 2) & 1;
  const int rg = blk & 3;
  const int cg = blk >> 3;
  const int rowbase = rg * RB;
  const int cgl = cg * 32 + colt * 16 + (lane & 15);
  const int kb8 = (lane >> 4) * 8;
  const int l15 = lane & 15;

  // LN params -> fp16, grouped layout [q][k][8]; b pre-scaled by ZSCALE
  for (int i = tid; i < H_; i += 512) {
    int kk = i >> 5, rem = i & 31, q = rem >> 3, j = rem & 7;
    int pi = q * 256 + kk * 8 + j;
    slnw0h[pi] = (_Float16)ln_w0[i];
    slnbz0h[pi] = (_Float16)(ZSCALE * ln_b0[i]);
    slnw1h[pi] = (_Float16)ln_w1[i];
    slnbz1h[pi] = (_Float16)(ZSCALE * ln_b1[i]);
  }

  float bias = 0.f;

  if (layer == 0) {
    // ===== LAYER 0 (unchanged from R18/R15) =====
    h16x8 WX[4], WH[8];
#pragma unroll
    for (int s = 0; s < 4; ++s) {
      WX[s] = ldw8h(W_ih0 + (size_t)cgl * IN_ + kh * 128 + s * 32 + kb8);
      PIN8(WX[s]);
    }
#pragma unroll
    for (int s = 0; s < 8; ++s) {
      WH[s] = ldw8h(W_hh0 + (size_t)cgl * H_ + kh * 256 + s * 32 + kb8);
      PIN8(WH[s]);
    }
    if (kh == 0) bias = b_ih0[cgl] + b_hh0[cgl];
    __syncthreads();

    for (int t = 0; t < T_; ++t) {
      stageXh(input + ((size_t)t * B_ + rowbase) * IN_, sA, tid);
      __syncthreads();
      f32x4 acc = (kh == 0) ? (f32x4){bias, bias, bias, bias} : (f32x4){0.f, 0.f, 0.f, 0.f};
#pragma unroll
      for (int s = 0; s < 4; ++s) acc = MFMA(AF(sA, kh * 128 + s * 32), WX[s], acc);
      if (tid == 0 && t > 0) poll32h(&flag0a[FL(t - 1, rg)], t);
      __syncthreads();
      if (t == 0) stageHf(hidden + (size_t)rowbase * H_, sA, tid);
      else stageLTh(pre0 + ((size_t)(t - 1) * B_ + rowbase) * H_, sA,
                    slnw0h, slnbz0h, tid, cg, false, nullptr, nullptr);
      __syncthreads();
#pragma unroll
      for (int s = 0; s < 8; ++s) acc = MFMA(AF(sA, kh * 256 + s * 32), WH[s], acc);
      if (kh > 0) {
#pragma unroll
        for (int j = 0; j < 4; ++j) sacc[kh - 1][colt][(lane >> 4) * 4 + j][l15] = acc[j];
      }
      __syncthreads();
      if (kh == 0) {
        ushort_t* dst = pre0 + ((size_t)t * B_ + rowbase) * H_;
#pragma unroll
        for (int j = 0; j < 4; ++j) {
          int row = (lane >> 4) * 4 + j;
          float v = acc[j] + sacc[0][colt][row][l15] + sacc[1][colt][row][l15] +
                    sacc[2][colt][row][l15];
          sth_sys(&dst[(size_t)row * H_ + cgl], v);
        }
        relfence();
      }
      __syncthreads();
      if (tid == 0) {
        stamp16(&flag0a[FL(t, rg) + cg], t + 1);
        stamp16(&flag0b[FL(t, rg) + cg], t + 1);
      }
    }
    // epilogue: h_fin[0] slice
    if (tid == 0) poll32h(&flag0a[FL(T_ - 1, rg)], T_);
    __syncthreads();
    stageLTh(pre0 + ((size_t)(T_ - 1) * B_ + rowbase) * H_, sA, slnw0h, slnbz0h, tid, cg, true,
             gout + (size_t)T_ * B_ * H_ + (size_t)rowbase * H_, nullptr);
  } else {
    // ===== LAYER 1 (R20 structure: prefetch pre0[t+1] in registers) =====
    h16x8 WB[8], WA[8];
#pragma unroll
    for (int s = 0; s < 8; ++s) {
      WB[s] = ldw8h(W_ih1 + (size_t)cgl * H_ + kh * 256 + s * 32 + kb8);
      PIN8(WB[s]);
    }
#pragma unroll
    for (int s = 0; s < 8; ++s) {
      WA[s] = ldw8h(W_hh1 + (size_t)cgl * H_ + kh * 256 + s * 32 + kb8);
      PIN8(WA[s]);
    }
    if (kh == 0) bias = b_ih1[cgl] + b_hh1[cgl];
    if (tid == 0) poll32h(&flag0b[FL(0, rg)], 1);  // verify pre0[0] before first prefetch
    __syncthreads();

    h16x8 raw0[4];  // pre0 slab prefetched one step ahead (carried across iterations)
    ldraw4(pre0 + ((size_t)0 * B_ + rowbase) * H_, raw0, tid);

    for (int t = 0; t < T_; ++t) {
      // ---- Phase S: procLT on prefetched pre0[t] -> sA (no load latency on chain).
      procLTh(raw0, sA, slnw0h, slnbz0h, tid, cg, false, nullptr, nullptr);
      if (tid == 0 && t + 1 < T_) poll32h(&flag0b[FL(t + 1, rg)], t + 2);
      if (tid == 64 && t > 0) poll32h(&flag1a[FL(t - 1, rg)], t);
      __syncthreads();  // bar2: sA ready + both polls done
      // ---- Merged phase: issue pre1[t-1] + prefetch pre0[t+1] loads, WB MFMA, procLT1
      f32x4 acc = (kh == 0) ? (f32x4){bias, bias, bias, bias} : (f32x4){0.f, 0.f, 0.f, 0.f};
      if (t + 1 < T_) ldraw4(pre0 + ((size_t)(t + 1) * B_ + rowbase) * H_, raw0, tid);
      if (t == 0) {
#pragma unroll
        for (int s = 0; s < 8; ++s) acc = MFMA(AF(sA, kh * 256 + s * 32), WB[s], acc);
        stageHf(hidden + (size_t)B_ * H_ + (size_t)rowbase * H_, sA1, tid);
      } else {
        h16x8 raw1[4];
        ldraw4(pre1 + ((size_t)(t - 1) * B_ + rowbase) * H_, raw1, tid);  // loads in flight
#pragma unroll
        for (int s = 0; s < 8; ++s) acc = MFMA(AF(sA, kh * 256 + s * 32), WB[s], acc);
        procLTh(raw1, sA1, slnw1h, slnbz1h, tid, cg, true,
                gout + ((size_t)(t - 1) * B_ + rowbase) * H_, nullptr);
      }
      __syncthreads();  // bar3: sA1 ready (WB done everywhere too)
#pragma unroll
      for (int s = 0; s < 8; ++s) acc = MFMA(AF(sA1, kh * 256 + s * 32), WA[s], acc);
      if (kh > 0) {
#pragma unroll
        for (int j = 0; j < 4; ++j) sacc[kh - 1][colt][(lane >> 4) * 4 + j][l15] = acc[j];
      }
      __syncthreads();  // bar4: sacc ready
      if (kh == 0) {
        ushort_t* dst = pre1 + ((size_t)t * B_ + rowbase) * H_;
#pragma unroll
        for (int j = 0; j < 4; ++j) {
          int row = (lane >> 4) * 4 + j;
          float v = acc[j] + sacc[0][colt][row][l15] + sacc[1][colt][row][l15] +
                    sacc[2][colt][row][l15];
          sth_sys(&dst[(size_t)row * H_ + cgl], v);
        }
        relfence();  // note: also waits the raw0 prefetch loads — both complete here
      }
      __syncthreads();  // bar5: stores drained (also fences sA overwrite next step)
      if (tid == 0) stamp16(&flag1a[FL(t, rg) + cg], t + 1);
    }
    // epilogue: gout[T-1] + h_fin[1] slices
    if (tid == 0) poll32h(&flag1a[FL(T_ - 1, rg)], T_);
    __syncthreads();
    stageLTh(pre1 + ((size_t)(T_ - 1) * B_ + rowbase) * H_, sA, slnw1h, slnbz1h, tid, cg, true,
             gout + ((size_t)(T_ - 1) * B_ + rowbase) * H_,
             gout + (size_t)T_ * B_ * H_ + (size_t)B_ * H_ + (size_t)rowbase * H_);
  }
}

extern "C" void kernel_launch(void* const* d_in, const int* in_sizes, int n_in,
                              void* d_out, int out_size, void* d_ws, size_t ws_size,
                              hipStream_t stream) {
  const float* input = (const float*)d_in[0];
  const float* hidden = (const float*)d_in[1];
  const float* W_ih0 = (const float*)d_in[2];
  const float* W_hh0 = (const float*)d_in[3];
  const float* b_ih0 = (const float*)d_in[4];
  const float* b_hh0 = (const float*)d_in[5];
  const float* ln_w0 = (const float*)d_in[6];
  const float* ln_b0 = (const float*)d_in[7];
  const float* W_ih1 = (const float*)d_in[8];
  const float* W_hh1 = (const float*)d_in[9];
  const float* b_ih1 = (const float*)d_in[10];
  const float* b_hh1 = (const float*)d_in[11];
  const float* ln_w1 = (const float*)d_in[12];
  const float* ln_b1 = (const float*)d_in[13];
  float* gout = (float*)d_out;

  const size_t slabT = (size_t)T_ * B_ * H_ * 2;  // 64 MB per no-wrap fp16 buffer
  char* ws = (char*)d_ws;
  ushort_t* pre0 = (ushort_t*)ws;
  ushort_t* pre1 = (ushort_t*)(ws + slabT);
  char* ctrl = ws + 2 * slabT;
  ushort_t* flag0a = (ushort_t*)ctrl;                  // 2048 lines x 64B = 128 KB
  ushort_t* flag0b = (ushort_t*)(ctrl + 0x20000);      // 128 KB
  ushort_t* flag1a = (ushort_t*)(ctrl + 0x40000);      // 128 KB

  (void)hipMemsetAsync(ctrl, 0, 0x60000, stream);
  hipLaunchKernelGGL(rnn_persist, dim3(256), dim3(512), 0, stream,
                     input, hidden, W_ih0, W_hh0, b_ih0, b_hh0, ln_w0, ln_b0,
                     W_ih1, W_hh1, b_ih1, b_hh1, ln_w1, ln_b1,
                     gout, pre0, pre1, flag0a, flag0b, flag1a);
}

// Round 22
// 2717.138 us; speedup vs baseline: 1.0206x; 1.0206x over previous
//
#include <hip/hip_runtime.h>
#include <stdint.h>

#define T_ 512
#define B_ 64
#define IN_ 512
#define H_ 1024
#define RB 16
#define LNEPS 1e-5f
#define ZSCALE 2.885390081777927f  // 2*log2(e): tanh(y) via exp2(z), z = ZSCALE*y
#define FL(t, rg) (((t) * 4 + (rg)) * 32)  // ushort index: 64B line, 32 u16 stamps

typedef __attribute__((ext_vector_type(8))) _Float16 h16x8;
typedef __attribute__((ext_vector_type(2))) _Float16 h16x2;
typedef __attribute__((ext_vector_type(4))) float f32x4;
typedef __attribute__((ext_vector_type(4))) float float4v;
typedef __attribute__((ext_vector_type(4))) int int4v;
typedef unsigned short ushort_t;

__device__ __forceinline__ h16x8 ldw8h(const float* p) {
  float4v a = *(const float4v*)p;
  float4v b = *(const float4v*)(p + 4);
  h16x8 o;
  o[0] = (_Float16)a[0]; o[1] = (_Float16)a[1]; o[2] = (_Float16)a[2]; o[3] = (_Float16)a[3];
  o[4] = (_Float16)b[0]; o[5] = (_Float16)b[1]; o[6] = (_Float16)b[2]; o[7] = (_Float16)b[3];
  return o;
}
#define PIN8(x) asm volatile("" : "+v"(x))

// ---- MALL-scope (sc0 sc1) stores + u16 stamp/poll sync (only safe inter-block point;
// R17 proved L2-scope signaling strands stamps in the producer's L2) ----
__device__ __forceinline__ void sth_sys(ushort_t* p, float v) {
  _Float16 h = (_Float16)v;
  int s = (int)__builtin_bit_cast(short, h);
  asm volatile("global_store_short %0, %1, off sc0 sc1" :: "v"(p), "v"(s) : "memory");
}
__device__ __forceinline__ void relfence() { asm volatile("s_waitcnt vmcnt(0)" ::: "memory"); }
__device__ __forceinline__ void stamp16(ushort_t* p, int v) {
  asm volatile("global_store_short %0, %1, off sc0 sc1" :: "v"(p), "v"(v) : "memory");
}
// poll one 64B line (32 u16 stamps) until min >= target
__device__ __forceinline__ void poll32h(const ushort_t* p, int target) {
  int n = 0;
  while (true) {
    int4v a, b, c, d;
    asm volatile(
        "global_load_dwordx4 %0, %4, off sc0 sc1\n\t"
        "global_load_dwordx4 %1, %4, off offset:16 sc0 sc1\n\t"
        "global_load_dwordx4 %2, %4, off offset:32 sc0 sc1\n\t"
        "global_load_dwordx4 %3, %4, off offset:48 sc0 sc1\n\t"
        "s_waitcnt vmcnt(0)"
        : "=&v"(a), "=&v"(b), "=&v"(c), "=&v"(d) : "v"(p) : "memory");
    int mn = 0xFFFF;
#pragma unroll
    for (int i = 0; i < 4; ++i) {
      unsigned u0 = (unsigned)a[i], u1 = (unsigned)b[i], u2 = (unsigned)c[i], u3 = (unsigned)d[i];
      mn = min(mn, (int)(u0 & 0xFFFFu)); mn = min(mn, (int)(u0 >> 16));
      mn = min(mn, (int)(u1 & 0xFFFFu)); mn = min(mn, (int)(u1 >> 16));
      mn = min(mn, (int)(u2 & 0xFFFFu)); mn = min(mn, (int)(u2 >> 16));
      mn = min(mn, (int)(u3 & 0xFFFFu)); mn = min(mn, (int)(u3 >> 16));
    }
    if (mn >= target) return;
    if (n < 4) __builtin_amdgcn_s_sleep(1);
    else __builtin_amdgcn_s_sleep(4);
    if (++n > 2000000) return;  // safety: wrong data instead of hang
  }
}

// LDS swizzle (ushort units): chunk = 8 u16 (16B); low2 = ((ch>>3)^ch^r)&3
__device__ __forceinline__ int chix(int r, int c) {
  int ch = c >> 3;
  int low = ((ch >> 3) ^ ch ^ r) & 3;
  return r * 1032 + ((((ch >> 2) << 2) | low) << 3) + (c & 7);
}

// ---- staging: 512 threads; r=tid>>5 in 0..15, k=tid&31 owns cols [32k,32k+32) ----
__device__ __forceinline__ void stageHf(const float* src, ushort_t* dA, int tid) {
  int r = tid >> 5, k = tid & 31, c0 = k * 32;
  const float* p = src + (size_t)r * H_ + c0;
#pragma unroll
  for (int q = 0; q < 4; ++q) {
    float4v a = *(const float4v*)(p + q * 8);
    float4v b = *(const float4v*)(p + q * 8 + 4);
    h16x8 h;
    h[0] = (_Float16)a[0]; h[1] = (_Float16)a[1]; h[2] = (_Float16)a[2]; h[3] = (_Float16)a[3];
    h[4] = (_Float16)b[0]; h[5] = (_Float16)b[1]; h[6] = (_Float16)b[2]; h[7] = (_Float16)b[3];
    *(h16x8*)&dA[chix(r, c0 + q * 8)] = h;
  }
}
__device__ __forceinline__ void stageXh(const float* src, ushort_t* dA, int tid) {
  int r = tid >> 5, k = tid & 31, c0 = k * 16;
  const float* p = src + (size_t)r * IN_ + c0;
#pragma unroll
  for (int q = 0; q < 2; ++q) {
    float4v a = *(const float4v*)(p + q * 8);
    float4v b = *(const float4v*)(p + q * 8 + 4);
    h16x8 h;
    h[0] = (_Float16)a[0]; h[1] = (_Float16)a[1]; h[2] = (_Float16)a[2]; h[3] = (_Float16)a[3];
    h[4] = (_Float16)b[0]; h[5] = (_Float16)b[1]; h[6] = (_Float16)b[2]; h[7] = (_Float16)b[3];
    *(h16x8*)&dA[chix(r, c0 + q * 8)] = h;
  }
}
// raw fp16 slab loads (plain path; write-once addresses)
__device__ __forceinline__ void ldraw4(const ushort_t* src, h16x8 (&raw)[4], int tid) {
  int r = tid >> 5, k = tid & 31, c0 = k * 32;
  const ushort_t* p = src + (size_t)r * H_ + c0;
#pragma unroll
  for (int q = 0; q < 4; ++q) raw[q] = *(const h16x8*)(p + q * 8);
}
// LN+tanh on a raw fp16 slab -> fp16 LDS. Packed-fp16 LN apply + dot2 stats + fp32 exp2 tail.
__device__ __forceinline__ void procLTh(const h16x8 (&raw)[4], ushort_t* dA,
                                        const _Float16* lnw, const _Float16* lnbz, int tid,
                                        int cg, bool wr, float* gA, float* gB) {
  int r = tid >> 5, k = tid & 31, c0 = k * 32;
  const h16x2 one2 = {(_Float16)1.f, (_Float16)1.f};
  float s = 0.f, ss = 0.f;
#pragma unroll
  for (int q = 0; q < 4; ++q) {
#pragma unroll
    for (int pp = 0; pp < 4; ++pp) {
      h16x2 xp;
      xp[0] = raw[q][2 * pp]; xp[1] = raw[q][2 * pp + 1];
      s = __builtin_amdgcn_fdot2(xp, one2, s, false);
      ss = __builtin_amdgcn_fdot2(xp, xp, ss, false);
    }
  }
#pragma unroll
  for (int m = 1; m <= 16; m <<= 1) { s += __shfl_xor(s, m, 64); ss += __shfl_xor(ss, m, 64); }
  float mu = s * (1.f / H_);
  float var = ss * (1.f / H_) - mu * mu;
  float zrs = rsqrtf(var + LNEPS) * ZSCALE;
  _Float16 muh = (_Float16)mu, zrsh = (_Float16)zrs;
  h16x2 mu2 = {muh, muh}, zrs2 = {zrsh, zrsh};
#pragma unroll
  for (int q = 0; q < 4; ++q) {
    h16x8 wv = *(const h16x8*)&lnw[q * 256 + k * 8];
    h16x8 bzv = *(const h16x8*)&lnbz[q * 256 + k * 8];
    h16x8 hout;
    float hf[8];
#pragma unroll
    for (int pp = 0; pp < 4; ++pp) {
      h16x2 xp, wp, bp;
      xp[0] = raw[q][2 * pp]; xp[1] = raw[q][2 * pp + 1];
      wp[0] = wv[2 * pp];     wp[1] = wv[2 * pp + 1];
      bp[0] = bzv[2 * pp];    bp[1] = bzv[2 * pp + 1];
      h16x2 z2 = (xp - mu2) * zrs2 * wp + bp;  // z = ZSCALE * y, packed fp16
#pragma unroll
      for (int e = 0; e < 2; ++e) {
        float z = (float)z2[e];
        z = fminf(15.8f, fmaxf(-15.8f, z));
        float ex = __builtin_amdgcn_exp2f(z);            // 2^z = e^{2y}
        float rr = __builtin_amdgcn_rcpf(ex + 1.f);
        float hv = __builtin_fmaf(-2.f, rr, 1.f);        // tanh(y)
        hout[2 * pp + e] = (_Float16)hv;
        hf[2 * pp + e] = hv;
      }
    }
    *(h16x8*)&dA[chix(r, c0 + q * 8)] = hout;
    if (wr && k == cg) {
      float* pa = gA + (size_t)r * H_ + c0 + q * 8;
      *(float4v*)pa = (float4v){hf[0], hf[1], hf[2], hf[3]};
      *(float4v*)(pa + 4) = (float4v){hf[4], hf[5], hf[6], hf[7]};
      if (gB) {
        float* pb = gB + (size_t)r * H_ + c0 + q * 8;
        *(float4v*)pb = (float4v){hf[0], hf[1], hf[2], hf[3]};
        *(float4v*)(pb + 4) = (float4v){hf[4], hf[5], hf[6], hf[7]};
      }
    }
  }
}
__device__ __forceinline__ void stageLTh(const ushort_t* src, ushort_t* dA,
                                         const _Float16* lnw, const _Float16* lnbz, int tid,
                                         int cg, bool wr, float* gA, float* gB) {
  h16x8 raw[4];
  ldraw4(src, raw, tid);
  procLTh(raw, dA, lnw, lnbz, tid, cg, wr, gA, gB);
}

#define MFMA(a, b, c) __builtin_amdgcn_mfma_f32_16x16x32_f16(a, b, c, 0, 0, 0)
#define AF(buf, idx) (*(const h16x8*)&buf[chix(lane & 15, (idx) + kb8)])

// geometry: 256 blocks; XCD-pinned mapping: layer=(blk>>2)&1, rg=blk&3, cg=blk>>3
__global__ __launch_bounds__(512, 1) void rnn_persist(
    const float* __restrict__ input, const float* __restrict__ hidden,
    const float* __restrict__ W_ih0, const float* __restrict__ W_hh0,
    const float* __restrict__ b_ih0, const float* __restrict__ b_hh0,
    const float* __restrict__ ln_w0, const float* __restrict__ ln_b0,
    const float* __restrict__ W_ih1, const float* __restrict__ W_hh1,
    const float* __restrict__ b_ih1, const float* __restrict__ b_hh1,
    const float* __restrict__ ln_w1, const float* __restrict__ ln_b1,
    float* gout, ushort_t* pre0, ushort_t* pre1,
    ushort_t* flag0a, ushort_t* flag0b, ushort_t* flag1a) {
  __shared__ ushort_t sA[16 * 1032];
  __shared__ ushort_t sA1[16 * 1032];   // L1 double buffer (stage1 overlaps WB MFMA)
  __shared__ _Float16 slnw0h[1024], slnbz0h[1024];
  __shared__ _Float16 slnw1h[1024], slnbz1h[1024];
  __shared__ float sacc[3][2][16][16];

  const int tid = threadIdx.x;
  const int lane = tid & 63;
  const int w = tid >> 6;
  const int colt = w & 1, kh = w >> 1;  // 2 col-tiles x 4 K-quarters
  const int blk = blockIdx.x;
  const int layer = (blk >> 2) & 1;
  const int rg = blk & 3;
  const int cg = blk >> 3;
  const int rowbase = rg * RB;
  const int cgl = cg * 32 + colt * 16 + (lane & 15);
  const int kb8 = (lane >> 4) * 8;
  const int l15 = lane & 15;

  // LN params -> fp16, grouped layout [q][k][8]; b pre-scaled by ZSCALE
  for (int i = tid; i < H_; i += 512) {
    int kk = i >> 5, rem = i & 31, q = rem >> 3, j = rem & 7;
    int pi = q * 256 + kk * 8 + j;
    slnw0h[pi] = (_Float16)ln_w0[i];
    slnbz0h[pi] = (_Float16)(ZSCALE * ln_b0[i]);
    slnw1h[pi] = (_Float16)ln_w1[i];
    slnbz1h[pi] = (_Float16)(ZSCALE * ln_b1[i]);
  }

  float bias = 0.f;

  if (layer == 0) {
    // ===== LAYER 0 (R15/R18 structure) =====
    h16x8 WX[4], WH[8];
#pragma unroll
    for (int s = 0; s < 4; ++s) {
      WX[s] = ldw8h(W_ih0 + (size_t)cgl * IN_ + kh * 128 + s * 32 + kb8);
      PIN8(WX[s]);
    }
#pragma unroll
    for (int s = 0; s < 8; ++s) {
      WH[s] = ldw8h(W_hh0 + (size_t)cgl * H_ + kh * 256 + s * 32 + kb8);
      PIN8(WH[s]);
    }
    if (kh == 0) bias = b_ih0[cgl] + b_hh0[cgl];
    __syncthreads();

    for (int t = 0; t < T_; ++t) {
      stageXh(input + ((size_t)t * B_ + rowbase) * IN_, sA, tid);
      __syncthreads();
      f32x4 acc = (kh == 0) ? (f32x4){bias, bias, bias, bias} : (f32x4){0.f, 0.f, 0.f, 0.f};
#pragma unroll
      for (int s = 0; s < 4; ++s) acc = MFMA(AF(sA, kh * 128 + s * 32), WX[s], acc);
      if (tid == 0 && t > 0) poll32h(&flag0a[FL(t - 1, rg)], t);
      __syncthreads();
      if (t == 0) stageHf(hidden + (size_t)rowbase * H_, sA, tid);
      else stageLTh(pre0 + ((size_t)(t - 1) * B_ + rowbase) * H_, sA,
                    slnw0h, slnbz0h, tid, cg, false, nullptr, nullptr);
      __syncthreads();
#pragma unroll
      for (int s = 0; s < 8; ++s) acc = MFMA(AF(sA, kh * 256 + s * 32), WH[s], acc);
      if (kh > 0) {
#pragma unroll
        for (int j = 0; j < 4; ++j) sacc[kh - 1][colt][(lane >> 4) * 4 + j][l15] = acc[j];
      }
      __syncthreads();
      if (kh == 0) {
        ushort_t* dst = pre0 + ((size_t)t * B_ + rowbase) * H_;
#pragma unroll
        for (int j = 0; j < 4; ++j) {
          int row = (lane >> 4) * 4 + j;
          float v = acc[j] + sacc[0][colt][row][l15] + sacc[1][colt][row][l15] +
                    sacc[2][colt][row][l15];
          sth_sys(&dst[(size_t)row * H_ + cgl], v);
        }
        relfence();
      }
      __syncthreads();
      if (tid == 0) {
        stamp16(&flag0a[FL(t, rg) + cg], t + 1);
        stamp16(&flag0b[FL(t, rg) + cg], t + 1);
      }
    }
    // epilogue: h_fin[0] slice
    if (tid == 0) poll32h(&flag0a[FL(T_ - 1, rg)], T_);
    __syncthreads();
    stageLTh(pre0 + ((size_t)(T_ - 1) * B_ + rowbase) * H_, sA, slnw0h, slnbz0h, tid, cg, true,
             gout + (size_t)T_ * B_ * H_ + (size_t)rowbase * H_, nullptr);
  } else {
    // ===== LAYER 1 (R20 structure: prefetch pre0[t+1] in registers) =====
    h16x8 WB[8], WA[8];
#pragma unroll
    for (int s = 0; s < 8; ++s) {
      WB[s] = ldw8h(W_ih1 + (size_t)cgl * H_ + kh * 256 + s * 32 + kb8);
      PIN8(WB[s]);
    }
#pragma unroll
    for (int s = 0; s < 8; ++s) {
      WA[s] = ldw8h(W_hh1 + (size_t)cgl * H_ + kh * 256 + s * 32 + kb8);
      PIN8(WA[s]);
    }
    if (kh == 0) bias = b_ih1[cgl] + b_hh1[cgl];
    if (tid == 0) poll32h(&flag0b[FL(0, rg)], 1);  // verify pre0[0] before first prefetch
    __syncthreads();

    h16x8 raw0[4];  // pre0 slab prefetched one step ahead (carried across iterations)
    ldraw4(pre0 + ((size_t)0 * B_ + rowbase) * H_, raw0, tid);

    for (int t = 0; t < T_; ++t) {
      // ---- Phase S: procLT on prefetched pre0[t] -> sA (no load latency on chain).
      procLTh(raw0, sA, slnw0h, slnbz0h, tid, cg, false, nullptr, nullptr);
      if (tid == 0 && t + 1 < T_) poll32h(&flag0b[FL(t + 1, rg)], t + 2);
      if (tid == 64 && t > 0) poll32h(&flag1a[FL(t - 1, rg)], t);
      __syncthreads();  // bar2: sA ready + both polls done
      // ---- Merged phase: issue pre1[t-1] + prefetch pre0[t+1] loads, WB MFMA, procLT1
      f32x4 acc = (kh == 0) ? (f32x4){bias, bias, bias, bias} : (f32x4){0.f, 0.f, 0.f, 0.f};
      if (t + 1 < T_) ldraw4(pre0 + ((size_t)(t + 1) * B_ + rowbase) * H_, raw0, tid);
      if (t == 0) {
#pragma unroll
        for (int s = 0; s < 8; ++s) acc = MFMA(AF(sA, kh * 256 + s * 32), WB[s], acc);
        stageHf(hidden + (size_t)B_ * H_ + (size_t)rowbase * H_, sA1, tid);
      } else {
        h16x8 raw1[4];
        ldraw4(pre1 + ((size_t)(t - 1) * B_ + rowbase) * H_, raw1, tid);  // loads in flight
#pragma unroll
        for (int s = 0; s < 8; ++s) acc = MFMA(AF(sA, kh * 256 + s * 32), WB[s], acc);
        procLTh(raw1, sA1, slnw1h, slnbz1h, tid, cg, true,
                gout + ((size_t)(t - 1) * B_ + rowbase) * H_, nullptr);
      }
      __syncthreads();  // bar3: sA1 ready (WB done everywhere too)
#pragma unroll
      for (int s = 0; s < 8; ++s) acc = MFMA(AF(sA1, kh * 256 + s * 32), WA[s], acc);
      if (kh > 0) {
#pragma unroll
        for (int j = 0; j < 4; ++j) sacc[kh - 1][colt][(lane >> 4) * 4 + j][l15] = acc[j];
      }
      __syncthreads();  // bar4: sacc ready
      if (kh == 0) {
        ushort_t* dst = pre1 + ((size_t)t * B_ + rowbase) * H_;
#pragma unroll
        for (int j = 0; j < 4; ++j) {
          int row = (lane >> 4) * 4 + j;
          float v = acc[j] + sacc[0][colt][row][l15] + sacc[1][colt][row][l15] +
                    sacc[2][colt][row][l15];
          sth_sys(&dst[(size_t)row * H_ + cgl], v);
        }
        relfence();  // note: also waits the raw0 prefetch loads — both complete here
      }
      __syncthreads();  // bar5: stores drained (also fences sA overwrite next step)
      if (tid == 0) stamp16(&flag1a[FL(t, rg) + cg], t + 1);
    }
    // epilogue: gout[T-1] + h_fin[1] slices
    if (tid == 0) poll32h(&flag1a[FL(T_ - 1, rg)], T_);
    __syncthreads();
    stageLTh(pre1 + ((size_t)(T_ - 1) * B_ + rowbase) * H_, sA, slnw1h, slnbz1h, tid, cg, true,
             gout + ((size_t)(T_ - 1) * B_ + rowbase) * H_,
             gout + (size_t)T_ * B_ * H_ + (size_t)B_ * H_ + (size_t)rowbase * H_);
  }
}

extern "C" void kernel_launch(void* const* d_in, const int* in_sizes, int n_in,
                              void* d_out, int out_size, void* d_ws, size_t ws_size,
                              hipStream_t stream) {
  const float* input = (const float*)d_in[0];
  const float* hidden = (const float*)d_in[1];
  const float* W_ih0 = (const float*)d_in[2];
  const float* W_hh0 = (const float*)d_in[3];
  const float* b_ih0 = (const float*)d_in[4];
  const float* b_hh0 = (const float*)d_in[5];
  const float* ln_w0 = (const float*)d_in[6];
  const float* ln_b0 = (const float*)d_in[7];
  const float* W_ih1 = (const float*)d_in[8];
  const float* W_hh1 = (const float*)d_in[9];
  const float* b_ih1 = (const float*)d_in[10];
  const float* b_hh1 = (const float*)d_in[11];
  const float* ln_w1 = (const float*)d_in[12];
  const float* ln_b1 = (const float*)d_in[13];
  float* gout = (float*)d_out;

  const size_t slabT = (size_t)T_ * B_ * H_ * 2;  // 64 MB per no-wrap fp16 buffer
  char* ws = (char*)d_ws;
  ushort_t* pre0 = (ushort_t*)ws;
  ushort_t* pre1 = (ushort_t*)(ws + slabT);
  char* ctrl = ws + 2 * slabT;
  ushort_t* flag0a = (ushort_t*)ctrl;                  // 2048 lines x 64B = 128 KB
  ushort_t* flag0b = (ushort_t*)(ctrl + 0x20000);      // 128 KB
  ushort_t* flag1a = (ushort_t*)(ctrl + 0x40000);      // 128 KB

  (void)hipMemsetAsync(ctrl, 0, 0x60000, stream);
  hipLaunchKernelGGL(rnn_persist, dim3(256), dim3(512), 0, stream,
                     input, hidden, W_ih0, W_hh0, b_ih0, b_hh0, ln_w0, ln_b0,
                     W_ih1, W_hh1, b_ih1, b_hh1, ln_w1, ln_b1,
                     gout, pre0, pre1, flag0a, flag0b, flag1a);
}